// Round 14
// baseline (198.687 us; speedup 1.0000x reference)
//
#include <hip/hip_runtime.h>
#include <hip/hip_bf16.h>

#define D_MODEL 256
#define NUM_HEADS 8
#define DIM_HEAD 32
#define SEQ 4096
#define BATCH 2
#define NROWS (BATCH * SEQ)              // 8192
#define LN_EPS 1e-6f
#define MASK_BIAS -1.0e9f
#define SCALE 0.17677669529663687f      // 1/sqrt(32)
#define LOG2E 1.4426950408889634f

typedef __attribute__((ext_vector_type(8))) short short8;   // 8 bf16 (4 VGPRs)
typedef __attribute__((ext_vector_type(4))) float f32x4;    // MFMA C/D

static __device__ __forceinline__ unsigned short f2b(float f) {
    union { __hip_bfloat16 b; unsigned short u; } cv;
    cv.b = __float2bfloat16(f);
    return cv.u;
}
static __device__ __forceinline__ unsigned int pk_bf16(float lo, float hi) {
    union { __hip_bfloat162 v; unsigned int u; } cv;
    cv.v = __float22bfloat162_rn(make_float2(lo, hi));
    return cv.u;
}
// raw v_exp_f32: 1 instruction (no libm fixup) — confirmed win in R12
static __device__ __forceinline__ float exp2_raw(float x) {
#if __has_builtin(__builtin_amdgcn_exp2f)
    return __builtin_amdgcn_exp2f(x);
#else
    float r;
    asm volatile("v_exp_f32 %0, %1" : "=v"(r) : "v"(x));
    return r;
#endif
}
// async global->LDS, 16B per lane; LDS dest = uniform base + lane*16
static __device__ __forceinline__ void load_lds16(const void* g, void* l) {
    __builtin_amdgcn_global_load_lds(
        (const __attribute__((address_space(1))) unsigned int*)g,
        (__attribute__((address_space(3))) unsigned int*)l, 16, 0, 0);
}

// ---------------------------------------------------------------------------
// Kernel 0: prep. Blocks 0..767: Wt[n_cat][k] = W_w[k][n] (bf16) + bias.
// Blocks 768..799: T2 = pad * (-1e9*scale*log2e).
// ---------------------------------------------------------------------------
__global__ __launch_bounds__(256) void prep_kernel(
    const float* __restrict__ Wq, const float* __restrict__ Wk,
    const float* __restrict__ Wv,
    const float* __restrict__ bq, const float* __restrict__ bk,
    const float* __restrict__ bv,
    const float* __restrict__ pad,
    unsigned short* __restrict__ Wt, float* __restrict__ biasc,
    float* __restrict__ T2)
{
    const int blk = blockIdx.x;
    const int t = threadIdx.x;
    if (blk < 768) {
        const int w = blk >> 8;          // 0=Q 1=K 2=V
        const int k = blk & 255;         // contraction index
        const float* W = (w == 0) ? Wq : (w == 1) ? Wk : Wv;
        Wt[(size_t)(w * 256 + t) * 256 + k] = f2b(W[(size_t)k * 256 + t]);
        if (k == 0) {
            const float* bb = (w == 0) ? bq : (w == 1) ? bk : bv;
            biasc[w * 256 + t] = bb[t];
        }
    } else {
        const int i = (blk - 768) * 256 + t;
        T2[i] = pad[i] * (MASK_BIAS * SCALE * LOG2E);
    }
}

// ---------------------------------------------------------------------------
// Kernel 1: QKV projection, bf16 MFMA GEMM, per-matrix store orientation.
// Grid = 128 row-blocks x 12 col-blocks(64 cols, matrix-uniform).
// Q/K blocks: C^T = Wt_tile x x^T (mfma(bf,af)) -> lane holds 4 consecutive
// dims for one x-row -> coalesced 8B stores into Qh/Kh[s][32].
// V blocks: C = x x Wt^T (mfma(af,bf)) -> lane holds 4 consecutive s for one
// dim -> 8B stores into Vt[d][s].
// ---------------------------------------------------------------------------
__global__ __launch_bounds__(256) void qkv_mfma_kernel(
    const float* __restrict__ x, const unsigned short* __restrict__ Wt,
    const float* __restrict__ biasc,
    unsigned short* __restrict__ Qh, unsigned short* __restrict__ Kh,
    unsigned short* __restrict__ Vt)
{
    const int lane = threadIdx.x & 63;
    const int wid  = threadIdx.x >> 6;
    const int c    = lane & 15;
    const int quad = lane >> 4;

    const int rb = blockIdx.x / 12;
    const int cb = blockIdx.x % 12;
    const int r0 = rb * 64 + wid * 16;       // wave rows r0..r0+15
    const int n0 = cb * 64;                  // 64 cols, single matrix
    const bool isV = (n0 >= 512);

    f32x4 acc[4];
    #pragma unroll
    for (int t = 0; t < 4; t++) acc[t] = (f32x4){0.f, 0.f, 0.f, 0.f};

    const float* xp0 = x + (size_t)(r0 + c) * D_MODEL + quad * 8;
    const unsigned short* wp0 = Wt + (size_t)(n0 + c) * 256 + quad * 8;

    if (!isV) {
        for (int k0 = 0; k0 < 256; k0 += 32) {
            const float4 a0 = *(const float4*)(xp0 + k0);
            const float4 a1 = *(const float4*)(xp0 + k0 + 4);
            union { unsigned int u[4]; short8 s; } af;
            af.u[0] = pk_bf16(a0.x, a0.y);
            af.u[1] = pk_bf16(a0.z, a0.w);
            af.u[2] = pk_bf16(a1.x, a1.y);
            af.u[3] = pk_bf16(a1.z, a1.w);
            #pragma unroll
            for (int t = 0; t < 4; t++) {
                const short8 bf = *(const short8*)(wp0 + (size_t)(16 * t) * 256 + k0);
                acc[t] = __builtin_amdgcn_mfma_f32_16x16x32_bf16(bf, af.s, acc[t], 0, 0, 0);
            }
        }
        // lane c = x-row, regs = dims (n0&255)+16t+quad*4+{0..3}
        const int row = r0 + c;
        const int bb = row >> 12;
        const int s  = row & (SEQ - 1);
        unsigned short* base = (n0 < 256) ? Qh : Kh;
        #pragma unroll
        for (int t = 0; t < 4; t++) {
            const int dim = (n0 & 255) + 16 * t + quad * 4;
            const int h = dim >> 5, d = dim & 31;
            const float4 b4 = *(const float4*)(biasc + n0 + 16 * t + quad * 4);
            const size_t bh = (size_t)(bb * NUM_HEADS + h);
            uint2 pk = make_uint2(pk_bf16(acc[t][0] + b4.x, acc[t][1] + b4.y),
                                  pk_bf16(acc[t][2] + b4.z, acc[t][3] + b4.w));
            *(uint2*)(base + (bh * SEQ + s) * DIM_HEAD + d) = pk;
        }
    } else {
        for (int k0 = 0; k0 < 256; k0 += 32) {
            const float4 a0 = *(const float4*)(xp0 + k0);
            const float4 a1 = *(const float4*)(xp0 + k0 + 4);
            union { unsigned int u[4]; short8 s; } af;
            af.u[0] = pk_bf16(a0.x, a0.y);
            af.u[1] = pk_bf16(a0.z, a0.w);
            af.u[2] = pk_bf16(a1.x, a1.y);
            af.u[3] = pk_bf16(a1.z, a1.w);
            #pragma unroll
            for (int t = 0; t < 4; t++) {
                const short8 bf = *(const short8*)(wp0 + (size_t)(16 * t) * 256 + k0);
                acc[t] = __builtin_amdgcn_mfma_f32_16x16x32_bf16(af.s, bf, acc[t], 0, 0, 0);
            }
        }
        // lane c = dim col, regs = rows r0+quad*4+{0..3}
        const int row = r0 + quad * 4;
        const int bb = row >> 12;
        const int s  = row & (SEQ - 1);
        #pragma unroll
        for (int t = 0; t < 4; t++) {
            const int dim = (n0 & 255) + 16 * t + c;
            const int h = dim >> 5, d = dim & 31;
            const float bv = biasc[n0 + 16 * t + c];
            const size_t bh = (size_t)(bb * NUM_HEADS + h);
            uint2 pk = make_uint2(pk_bf16(acc[t][0] + bv, acc[t][1] + bv),
                                  pk_bf16(acc[t][2] + bv, acc[t][3] + bv));
            *(uint2*)(Vt + (bh * DIM_HEAD + d) * SEQ + s) = pk;
        }
    }
}

// ---------------------------------------------------------------------------
// Kernel 2: MFMA flash attention v7 — async LDS staging + cross-block
// key-split. Block = 64 queries x HALF the keys (e = gw&1); grid 2048 ->
// 8 blocks/CU. Partial (un-normalized O, denominator L) written to
// P1(=d_out)/L1 or P2/L2; ln fuses the linear combine. Math per R12/R13
// (perm trick, ones-MFMA denominator, raw v_exp_f32, XOR-swizzled staging).
// ---------------------------------------------------------------------------
__global__ __launch_bounds__(256, 8) void attn_mfma_kernel(
    const unsigned short* __restrict__ Qh, const unsigned short* __restrict__ Kh,
    const unsigned short* __restrict__ Vt, const float* __restrict__ T2,
    float* __restrict__ P1, float* __restrict__ P2,
    float* __restrict__ L1, float* __restrict__ L2)
{
    __shared__ __align__(16) unsigned short ldsK[2][64 * 32];  // 2x4KB
    __shared__ __align__(16) unsigned short ldsV[2][32 * 64];  // 2x4KB
    __shared__ __align__(16) float          ldsT[2][64];       // 2x256B

    const int lane = threadIdx.x & 63;
    const int wid  = threadIdx.x >> 6;
    const int c    = lane & 15;
    const int quad = lane >> 4;

    const int gw = blockIdx.x;                   // 0..2047
    const int e  = gw & 1;                       // key half
    const int q0 = ((gw >> 1) & 63) * 64;
    const int h  = (gw >> 7) & (NUM_HEADS - 1);
    const int b  = gw >> 10;
    const size_t bh = (size_t)(b * NUM_HEADS + h);

    const float k2 = SCALE * LOG2E;
    const int perm = ((c & 12) << 1) | (c & 3);  // pi(c)

    const unsigned short* Kb = Kh + bh * SEQ * DIM_HEAD;
    const unsigned short* Vb = Vt + bh * DIM_HEAD * SEQ;
    const float* Tb = T2 + (size_t)b * SEQ;
    const int sbase = e * (SEQ / 2);

    const int qrow = q0 + wid * 16;
    const short8 qf = *(const short8*)(Qh + (bh * SEQ + qrow + c) * DIM_HEAD + quad * 8);

    union { unsigned int u[4]; short8 s; } ones;
    ones.u[0] = ones.u[1] = ones.u[2] = ones.u[3] = 0x3F803F80u;  // bf16 1.0 x2

    // loop-invariant LDS read offsets (elements)
    const int f0 = ((perm >> 1) ^ (perm >> 3)) & 3;
    const int f1 = (((perm + 4) >> 1) ^ ((perm + 4) >> 3)) & 3;
    const int kA = perm * 32 + ((quad ^ f0) << 3);        // + sub*1024
    const int kB = (perm + 4) * 32 + ((quad ^ f1) << 3);
    const int g0 = quad ^ (c & 7);
    const int vA0 = c * 64 + (g0 << 3);
    const int vA1 = c * 64 + ((g0 ^ 4) << 3);
    const int vB0 = (16 + c) * 64 + (g0 << 3);
    const int vB1 = (16 + c) * 64 + ((g0 ^ 4) << 3);

    // staging lane constants
    const int skey = (lane >> 2);
    const int sgK  = lane & 3;
    const int sdim = lane >> 3;
    const int sgV  = lane & 7;

    f32x4 o0 = {0.f,0.f,0.f,0.f}, o1 = {0.f,0.f,0.f,0.f};
    f32x4 lacc = {0.f,0.f,0.f,0.f};
    const f32x4 z = {0.f, 0.f, 0.f, 0.f};

    auto stage = [&](int lch, int pb) {
        const int s0 = sbase + lch * 64;
        if (wid < 2) {
            #pragma unroll
            for (int jj = 0; jj < 2; jj++) {
                const int j = wid * 2 + jj;
                const int key = j * 16 + skey;
                const int f = ((key >> 1) ^ (key >> 3)) & 3;
                load_lds16(Kb + (size_t)(s0 + key) * 32 + ((sgK ^ f) << 3),
                           &ldsK[pb][j * 512]);
            }
        } else {
            #pragma unroll
            for (int jj = 0; jj < 2; jj++) {
                const int j = (wid - 2) * 2 + jj;
                const int dim = j * 8 + sdim;
                load_lds16(Vb + (size_t)dim * SEQ + s0 + ((sgV ^ (dim & 7)) << 3),
                           &ldsV[pb][j * 512]);
            }
            if (wid == 3 && lane < 16)
                load_lds16(Tb + s0 + lane * 4, &ldsT[pb][0]);
        }
    };

    auto sub = [&](int pb, int s) {
        const short8 kf0 = *(const short8*)&ldsK[pb][s * 1024 + kA];
        const short8 kf1 = *(const short8*)&ldsK[pb][s * 1024 + kB];
        const short8 vf0 = *(const short8*)&ldsV[pb][s ? vA1 : vA0];
        const short8 vf1 = *(const short8*)&ldsV[pb][s ? vB1 : vB0];
        const float4 t0 = *(const float4*)&ldsT[pb][s * 32 + quad * 8];
        const float4 t1 = *(const float4*)&ldsT[pb][s * 32 + quad * 8 + 4];

        const f32x4 st0 = __builtin_amdgcn_mfma_f32_16x16x32_bf16(kf0, qf, z, 0, 0, 0);
        const f32x4 st1 = __builtin_amdgcn_mfma_f32_16x16x32_bf16(kf1, qf, z, 0, 0, 0);

        float p[8];
        p[0] = exp2_raw(fmaf(st0[0], k2, t0.x));
        p[1] = exp2_raw(fmaf(st0[1], k2, t0.y));
        p[2] = exp2_raw(fmaf(st0[2], k2, t0.z));
        p[3] = exp2_raw(fmaf(st0[3], k2, t0.w));
        p[4] = exp2_raw(fmaf(st1[0], k2, t1.x));
        p[5] = exp2_raw(fmaf(st1[1], k2, t1.y));
        p[6] = exp2_raw(fmaf(st1[2], k2, t1.z));
        p[7] = exp2_raw(fmaf(st1[3], k2, t1.w));

        union { unsigned int u[4]; short8 s8; } pf;
        pf.u[0] = pk_bf16(p[0], p[1]);
        pf.u[1] = pk_bf16(p[2], p[3]);
        pf.u[2] = pk_bf16(p[4], p[5]);
        pf.u[3] = pk_bf16(p[6], p[7]);

        lacc = __builtin_amdgcn_mfma_f32_16x16x32_bf16(ones.s, pf.s8, lacc, 0, 0, 0);
        o0   = __builtin_amdgcn_mfma_f32_16x16x32_bf16(vf0,   pf.s8, o0,   0, 0, 0);
        o1   = __builtin_amdgcn_mfma_f32_16x16x32_bf16(vf1,   pf.s8, o1,   0, 0, 0);
    };

    stage(0, 0);
    __syncthreads();
    for (int ch = 0; ch < 32; ++ch) {
        const int pb = ch & 1;
        stage((ch + 1) & 31, pb ^ 1);    // async prefetch into other buffer
        sub(pb, 0);
        sub(pb, 1);
        __syncthreads();                 // drains vmcnt; fences both buffers
    }

    // un-normalized partial store; combine happens in ln
    float* Pe = e ? P2 : P1;
    float* op = Pe + ((size_t)(b * SEQ) + qrow + c) * D_MODEL + h * DIM_HEAD + quad * 4;
    *(float4*)op        = make_float4(o0[0], o0[1], o0[2], o0[3]);
    *(float4*)(op + 16) = make_float4(o1[0], o1[1], o1[2], o1[3]);
    if (quad == 0) {
        float* Le = e ? L2 : L1;
        Le[((size_t)(b * SEQ) + qrow + c) * NUM_HEADS + h] = lacc[0];
    }
}

// ---------------------------------------------------------------------------
// Kernel 3: combine key-split partials + residual add + LayerNorm.
// In place on P1 (= d_out).
// ---------------------------------------------------------------------------
__global__ __launch_bounds__(256) void ln_kernel(
    float* P1,                     // aliased read/write — no restrict
    const float* __restrict__ P2,
    const float* __restrict__ L1, const float* __restrict__ L2,
    const float* __restrict__ x,
    const float* __restrict__ gamma, const float* __restrict__ beta)
{
    const int lane = threadIdx.x & 63;
    const int wid  = threadIdx.x >> 6;
    const size_t row = (size_t)blockIdx.x * 4 + wid;
    const int h = lane >> 3;                  // head of dims lane*4..lane*4+3

    const float4 a  = ((const float4*)(P1 + row * D_MODEL))[lane];
    const float4 p2 = ((const float4*)(P2 + row * D_MODEL))[lane];
    const float4 xv = ((const float4*)(x + row * D_MODEL))[lane];
    const float inv = 1.0f / (L1[row * NUM_HEADS + h] + L2[row * NUM_HEADS + h]);

    float hv[4];
    hv[0] = (a.x + p2.x) * inv + xv.x;
    hv[1] = (a.y + p2.y) * inv + xv.y;
    hv[2] = (a.z + p2.z) * inv + xv.z;
    hv[3] = (a.w + p2.w) * inv + xv.w;

    float s = hv[0] + hv[1] + hv[2] + hv[3];
    #pragma unroll
    for (int off = 32; off > 0; off >>= 1) s += __shfl_xor(s, off, 64);
    const float mu = s * (1.0f / D_MODEL);

    float d0 = hv[0]-mu, d1 = hv[1]-mu, d2 = hv[2]-mu, d3 = hv[3]-mu;
    float ss = d0*d0 + d1*d1 + d2*d2 + d3*d3;
    #pragma unroll
    for (int off = 32; off > 0; off >>= 1) ss += __shfl_xor(ss, off, 64);
    const float rs = rsqrtf(ss * (1.0f / D_MODEL) + LN_EPS);

    const float4 g  = ((const float4*)gamma)[lane];
    const float4 bb = ((const float4*)beta)[lane];
    float4 y;
    y.x = g.x * d0 * rs + bb.x;
    y.y = g.y * d1 * rs + bb.y;
    y.z = g.z * d2 * rs + bb.z;
    y.w = g.w * d3 * rs + bb.w;
    ((float4*)(P1 + row * D_MODEL))[lane] = y;
}

// ---------------------------------------------------------------------------
extern "C" void kernel_launch(void* const* d_in, const int* in_sizes, int n_in,
                              void* d_out, int out_size, void* d_ws, size_t ws_size,
                              hipStream_t stream)
{
    const float* x     = (const float*)d_in[0];
    const float* pad   = (const float*)d_in[1];
    const float* Wq    = (const float*)d_in[2];
    const float* bq    = (const float*)d_in[3];
    const float* Wk    = (const float*)d_in[4];
    const float* bk    = (const float*)d_in[5];
    const float* Wv    = (const float*)d_in[6];
    const float* bv    = (const float*)d_in[7];
    const float* gamma = (const float*)d_in[8];
    const float* beta  = (const float*)d_in[9];

    const size_t elems = (size_t)NROWS * D_MODEL;       // 2M
    unsigned short* Qh = (unsigned short*)d_ws;          // 4 MB
    unsigned short* Kh = Qh + elems;                     // 4 MB
    unsigned short* Vt = Kh + elems;                     // 4 MB
    float* T2 = (float*)(Vt + elems);                    // 32 KB
    unsigned short* Wt = (unsigned short*)(T2 + NROWS);  // 384 KB
    float* biasc = (float*)(Wt + 768 * 256);             // 3 KB
    float* P2 = biasc + 768;                             // 8 MB
    float* L1 = P2 + elems;                              // 256 KB
    float* L2 = L1 + (size_t)NROWS * NUM_HEADS;          // 256 KB
    float* P1 = (float*)d_out;                           // partial 1 + final out

    prep_kernel<<<800, 256, 0, stream>>>(Wq, Wk, Wv, bq, bk, bv, pad,
                                         Wt, biasc, T2);
    qkv_mfma_kernel<<<(NROWS / 64) * 12, 256, 0, stream>>>(x, Wt, biasc,
                                                           Qh, Kh, Vt);
    attn_mfma_kernel<<<BATCH * NUM_HEADS * (SEQ / 64) * 2, 256, 0, stream>>>(
        Qh, Kh, Vt, T2, P1, P2, L1, L2);
    ln_kernel<<<NROWS / 4, 256, 0, stream>>>(P1, P2, L1, L2, x, gamma, beta);
}

// Round 15
// 197.865 us; speedup vs baseline: 1.0042x; 1.0042x over previous
//
#include <hip/hip_runtime.h>
#include <hip/hip_bf16.h>

#define D_MODEL 256
#define NUM_HEADS 8
#define DIM_HEAD 32
#define SEQ 4096
#define BATCH 2
#define NROWS (BATCH * SEQ)              // 8192
#define LN_EPS 1e-6f
#define MASK_BIAS -1.0e9f
#define SCALE 0.17677669529663687f      // 1/sqrt(32)
#define LOG2E 1.4426950408889634f

typedef __attribute__((ext_vector_type(8))) short short8;   // 8 bf16 (4 VGPRs)
typedef __attribute__((ext_vector_type(4))) float f32x4;    // MFMA C/D

static __device__ __forceinline__ unsigned short f2b(float f) {
    union { __hip_bfloat16 b; unsigned short u; } cv;
    cv.b = __float2bfloat16(f);
    return cv.u;
}
static __device__ __forceinline__ unsigned int pk_bf16(float lo, float hi) {
    union { __hip_bfloat162 v; unsigned int u; } cv;
    cv.v = __float22bfloat162_rn(make_float2(lo, hi));
    return cv.u;
}
// raw v_exp_f32: 1 instruction (no libm fixup) — confirmed win in R12
static __device__ __forceinline__ float exp2_raw(float x) {
#if __has_builtin(__builtin_amdgcn_exp2f)
    return __builtin_amdgcn_exp2f(x);
#else
    float r;
    asm volatile("v_exp_f32 %0, %1" : "=v"(r) : "v"(x));
    return r;
#endif
}
// async global->LDS, 16B per lane; LDS dest = uniform base + lane*16
static __device__ __forceinline__ void load_lds16(const void* g, void* l) {
    __builtin_amdgcn_global_load_lds(
        (const __attribute__((address_space(1))) unsigned int*)g,
        (__attribute__((address_space(3))) unsigned int*)l, 16, 0, 0);
}

// ---------------------------------------------------------------------------
// Kernel 0: prep+cast. Blocks 0..767: Wt[n_cat][k] = W_w[k][n] (bf16) + bias.
// Blocks 768..799: T2 = pad * (-1e9*scale*log2e).
// Blocks 800..1823: xc = bf16(x)  (2M elems, 8 per thread).
// ---------------------------------------------------------------------------
__global__ __launch_bounds__(256) void prep_kernel(
    const float* __restrict__ Wq, const float* __restrict__ Wk,
    const float* __restrict__ Wv,
    const float* __restrict__ bq, const float* __restrict__ bk,
    const float* __restrict__ bv,
    const float* __restrict__ pad, const float* __restrict__ x,
    unsigned short* __restrict__ Wt, float* __restrict__ biasc,
    float* __restrict__ T2, unsigned short* __restrict__ xc)
{
    const int blk = blockIdx.x;
    const int t = threadIdx.x;
    if (blk < 768) {
        const int w = blk >> 8;          // 0=Q 1=K 2=V
        const int k = blk & 255;         // contraction index
        const float* W = (w == 0) ? Wq : (w == 1) ? Wk : Wv;
        Wt[(size_t)(w * 256 + t) * 256 + k] = f2b(W[(size_t)k * 256 + t]);
        if (k == 0) {
            const float* bb = (w == 0) ? bq : (w == 1) ? bk : bv;
            biasc[w * 256 + t] = bb[t];
        }
    } else if (blk < 800) {
        const int i = (blk - 768) * 256 + t;
        T2[i] = pad[i] * (MASK_BIAS * SCALE * LOG2E);
    } else {
        const size_t i8 = (size_t)(blk - 800) * 256 + t;   // uint4 index
        const float4 a0 = ((const float4*)x)[i8 * 2];
        const float4 a1 = ((const float4*)x)[i8 * 2 + 1];
        uint4 o;
        o.x = pk_bf16(a0.x, a0.y);
        o.y = pk_bf16(a0.z, a0.w);
        o.z = pk_bf16(a1.x, a1.y);
        o.w = pk_bf16(a1.z, a1.w);
        ((uint4*)xc)[i8] = o;
    }
}

// ---------------------------------------------------------------------------
// Kernel 1: QKV projection, bf16 MFMA GEMM from pre-cast xc.
// Grid = 128 row-blocks x 12 col-blocks (64 cols, matrix-uniform).
// Q/K blocks: C^T = Wt_tile x xc^T -> coalesced 8B stores into Qh/Kh[s][32].
// V blocks: C = xc x Wt^T -> 8B stores into Vt[d][s].
// ---------------------------------------------------------------------------
__global__ __launch_bounds__(256) void qkv_mfma_kernel(
    const unsigned short* __restrict__ xc, const unsigned short* __restrict__ Wt,
    const float* __restrict__ biasc,
    unsigned short* __restrict__ Qh, unsigned short* __restrict__ Kh,
    unsigned short* __restrict__ Vt)
{
    const int lane = threadIdx.x & 63;
    const int wid  = threadIdx.x >> 6;
    const int c    = lane & 15;
    const int quad = lane >> 4;

    const int rb = blockIdx.x / 12;
    const int cb = blockIdx.x % 12;
    const int r0 = rb * 64 + wid * 16;       // wave rows r0..r0+15
    const int n0 = cb * 64;                  // 64 cols, single matrix
    const bool isV = (n0 >= 512);

    f32x4 acc[4];
    #pragma unroll
    for (int t = 0; t < 4; t++) acc[t] = (f32x4){0.f, 0.f, 0.f, 0.f};

    const unsigned short* xp0 = xc + (size_t)(r0 + c) * D_MODEL + quad * 8;
    const unsigned short* wp0 = Wt + (size_t)(n0 + c) * 256 + quad * 8;

    if (!isV) {
        for (int k0 = 0; k0 < 256; k0 += 32) {
            const short8 af = *(const short8*)(xp0 + k0);
            #pragma unroll
            for (int t = 0; t < 4; t++) {
                const short8 bf = *(const short8*)(wp0 + (size_t)(16 * t) * 256 + k0);
                acc[t] = __builtin_amdgcn_mfma_f32_16x16x32_bf16(bf, af, acc[t], 0, 0, 0);
            }
        }
        // lane c = x-row, regs = dims (n0&255)+16t+quad*4+{0..3}
        const int row = r0 + c;
        const int bb = row >> 12;
        const int s  = row & (SEQ - 1);
        unsigned short* base = (n0 < 256) ? Qh : Kh;
        #pragma unroll
        for (int t = 0; t < 4; t++) {
            const int dim = (n0 & 255) + 16 * t + quad * 4;
            const int h = dim >> 5, d = dim & 31;
            const float4 b4 = *(const float4*)(biasc + n0 + 16 * t + quad * 4);
            const size_t bh = (size_t)(bb * NUM_HEADS + h);
            uint2 pk = make_uint2(pk_bf16(acc[t][0] + b4.x, acc[t][1] + b4.y),
                                  pk_bf16(acc[t][2] + b4.z, acc[t][3] + b4.w));
            *(uint2*)(base + (bh * SEQ + s) * DIM_HEAD + d) = pk;
        }
    } else {
        for (int k0 = 0; k0 < 256; k0 += 32) {
            const short8 af = *(const short8*)(xp0 + k0);
            #pragma unroll
            for (int t = 0; t < 4; t++) {
                const short8 bf = *(const short8*)(wp0 + (size_t)(16 * t) * 256 + k0);
                acc[t] = __builtin_amdgcn_mfma_f32_16x16x32_bf16(af, bf, acc[t], 0, 0, 0);
            }
        }
        // lane c = dim col, regs = rows r0+quad*4+{0..3}
        const int row = r0 + quad * 4;
        const int bb = row >> 12;
        const int s  = row & (SEQ - 1);
        #pragma unroll
        for (int t = 0; t < 4; t++) {
            const int dim = (n0 & 255) + 16 * t + c;
            const int h = dim >> 5, d = dim & 31;
            const float bv = biasc[n0 + 16 * t + c];
            const size_t bh = (size_t)(bb * NUM_HEADS + h);
            uint2 pk = make_uint2(pk_bf16(acc[t][0] + bv, acc[t][1] + bv),
                                  pk_bf16(acc[t][2] + bv, acc[t][3] + bv));
            *(uint2*)(Vt + (bh * DIM_HEAD + d) * SEQ + s) = pk;
        }
    }
}

// ---------------------------------------------------------------------------
// Kernel 2: MFMA flash attention v8 — async LDS staging with POINTER-BUMP
// sources (no per-chunk address math). Block = 64 queries x half the keys;
// grid 2048 (8 blocks/CU). Final prefetch overshoots into adjacent ws
// regions (readable, discarded). Partials to P1/P2 + L1/L2; ln combines.
// ---------------------------------------------------------------------------
__global__ __launch_bounds__(256, 8) void attn_mfma_kernel(
    const unsigned short* __restrict__ Qh, const unsigned short* __restrict__ Kh,
    const unsigned short* __restrict__ Vt, const float* __restrict__ T2,
    float* __restrict__ P1, float* __restrict__ P2,
    float* __restrict__ L1, float* __restrict__ L2)
{
    __shared__ __align__(16) unsigned short ldsK[2][64 * 32];  // 2x4KB
    __shared__ __align__(16) unsigned short ldsV[2][32 * 64];  // 2x4KB
    __shared__ __align__(16) float          ldsT[2][64];       // 2x256B

    const int lane = threadIdx.x & 63;
    const int wid  = threadIdx.x >> 6;
    const int c    = lane & 15;
    const int quad = lane >> 4;

    const int gw = blockIdx.x;                   // 0..2047
    const int e  = gw & 1;                       // key half
    const int q0 = ((gw >> 1) & 63) * 64;
    const int h  = (gw >> 7) & (NUM_HEADS - 1);
    const int b  = gw >> 10;
    const size_t bh = (size_t)(b * NUM_HEADS + h);

    const float k2 = SCALE * LOG2E;
    const int perm = ((c & 12) << 1) | (c & 3);  // pi(c)

    const unsigned short* Kb = Kh + bh * SEQ * DIM_HEAD;
    const unsigned short* Vb = Vt + bh * DIM_HEAD * SEQ;
    const float* Tb = T2 + (size_t)b * SEQ;
    const int sbase = e * (SEQ / 2);

    const int qrow = q0 + wid * 16;
    const short8 qf = *(const short8*)(Qh + (bh * SEQ + qrow + c) * DIM_HEAD + quad * 8);

    union { unsigned int u[4]; short8 s; } ones;
    ones.u[0] = ones.u[1] = ones.u[2] = ones.u[3] = 0x3F803F80u;  // bf16 1.0 x2

    // loop-invariant LDS read offsets (elements)
    const int f0 = ((perm >> 1) ^ (perm >> 3)) & 3;
    const int f1 = (((perm + 4) >> 1) ^ ((perm + 4) >> 3)) & 3;
    const int kA = perm * 32 + ((quad ^ f0) << 3);        // + sub*1024
    const int kB = (perm + 4) * 32 + ((quad ^ f1) << 3);
    const int g0i = quad ^ (c & 7);
    const int vA0 = c * 64 + (g0i << 3);
    const int vA1 = c * 64 + ((g0i ^ 4) << 3);
    const int vB0 = (16 + c) * 64 + (g0i << 3);
    const int vB1 = (16 + c) * 64 + ((g0i ^ 4) << 3);

    // ---- pointer-bump staging sources (precomputed once, bumped per chunk)
    const unsigned short *gp0, *gp1;
    const float* gT = Tb + sbase + lane * 4;     // used by wid==3, lane<16
    int d0ofs, d1ofs;                            // LDS dest plane offsets (elems)
    if (wid < 2) {
        const int skey = lane >> 2, sgK = lane & 3;
        const int key0 = (wid * 2)     * 16 + skey;
        const int key1 = (wid * 2 + 1) * 16 + skey;
        const int fa = ((key0 >> 1) ^ (key0 >> 3)) & 3;
        const int fb = ((key1 >> 1) ^ (key1 >> 3)) & 3;
        gp0 = Kb + (size_t)(sbase + key0) * 32 + ((sgK ^ fa) << 3);
        gp1 = Kb + (size_t)(sbase + key1) * 32 + ((sgK ^ fb) << 3);
        d0ofs = (wid * 2) * 512;
        d1ofs = (wid * 2 + 1) * 512;
    } else {
        const int sdim = lane >> 3, sgV = lane & 7;
        const int dim0 = ((wid - 2) * 2)     * 8 + sdim;
        const int dim1 = ((wid - 2) * 2 + 1) * 8 + sdim;
        gp0 = Vb + (size_t)dim0 * SEQ + sbase + ((sgV ^ (dim0 & 7)) << 3);
        gp1 = Vb + (size_t)dim1 * SEQ + sbase + ((sgV ^ (dim1 & 7)) << 3);
        d0ofs = ((wid - 2) * 2) * 512;
        d1ofs = ((wid - 2) * 2 + 1) * 512;
    }

    f32x4 o0 = {0.f,0.f,0.f,0.f}, o1 = {0.f,0.f,0.f,0.f};
    f32x4 lacc = {0.f,0.f,0.f,0.f};
    const f32x4 z = {0.f, 0.f, 0.f, 0.f};

    auto stage = [&](int pb) {
        if (wid < 2) {
            load_lds16(gp0, &ldsK[pb][d0ofs]);
            load_lds16(gp1, &ldsK[pb][d1ofs]);
            gp0 += 64 * 32; gp1 += 64 * 32;
        } else {
            load_lds16(gp0, &ldsV[pb][d0ofs]);
            load_lds16(gp1, &ldsV[pb][d1ofs]);
            gp0 += 64; gp1 += 64;
            if (wid == 3) {
                if (lane < 16) load_lds16(gT, &ldsT[pb][0]);
                gT += 64;
            }
        }
    };

    auto sub = [&](int pb, int s) {
        const short8 kf0 = *(const short8*)&ldsK[pb][s * 1024 + kA];
        const short8 kf1 = *(const short8*)&ldsK[pb][s * 1024 + kB];
        const short8 vf0 = *(const short8*)&ldsV[pb][s ? vA1 : vA0];
        const short8 vf1 = *(const short8*)&ldsV[pb][s ? vB1 : vB0];
        const float4 t0 = *(const float4*)&ldsT[pb][s * 32 + quad * 8];
        const float4 t1 = *(const float4*)&ldsT[pb][s * 32 + quad * 8 + 4];

        const f32x4 st0 = __builtin_amdgcn_mfma_f32_16x16x32_bf16(kf0, qf, z, 0, 0, 0);
        const f32x4 st1 = __builtin_amdgcn_mfma_f32_16x16x32_bf16(kf1, qf, z, 0, 0, 0);

        float p[8];
        p[0] = exp2_raw(fmaf(st0[0], k2, t0.x));
        p[1] = exp2_raw(fmaf(st0[1], k2, t0.y));
        p[2] = exp2_raw(fmaf(st0[2], k2, t0.z));
        p[3] = exp2_raw(fmaf(st0[3], k2, t0.w));
        p[4] = exp2_raw(fmaf(st1[0], k2, t1.x));
        p[5] = exp2_raw(fmaf(st1[1], k2, t1.y));
        p[6] = exp2_raw(fmaf(st1[2], k2, t1.z));
        p[7] = exp2_raw(fmaf(st1[3], k2, t1.w));

        union { unsigned int u[4]; short8 s8; } pf;
        pf.u[0] = pk_bf16(p[0], p[1]);
        pf.u[1] = pk_bf16(p[2], p[3]);
        pf.u[2] = pk_bf16(p[4], p[5]);
        pf.u[3] = pk_bf16(p[6], p[7]);

        lacc = __builtin_amdgcn_mfma_f32_16x16x32_bf16(ones.s, pf.s8, lacc, 0, 0, 0);
        o0   = __builtin_amdgcn_mfma_f32_16x16x32_bf16(vf0,   pf.s8, o0,   0, 0, 0);
        o1   = __builtin_amdgcn_mfma_f32_16x16x32_bf16(vf1,   pf.s8, o1,   0, 0, 0);
    };

    stage(0);
    __syncthreads();
    #pragma unroll 2
    for (int ch = 0; ch < 32; ++ch) {
        const int pb = ch & 1;
        stage(pb ^ 1);                   // async prefetch (last call overshoots)
        sub(pb, 0);
        sub(pb, 1);
        __syncthreads();                 // drains vmcnt; fences both buffers
    }

    // un-normalized partial store; combine happens in ln
    float* Pe = e ? P2 : P1;
    float* op = Pe + ((size_t)(b * SEQ) + qrow + c) * D_MODEL + h * DIM_HEAD + quad * 4;
    *(float4*)op        = make_float4(o0[0], o0[1], o0[2], o0[3]);
    *(float4*)(op + 16) = make_float4(o1[0], o1[1], o1[2], o1[3]);
    if (quad == 0) {
        float* Le = e ? L2 : L1;
        Le[((size_t)(b * SEQ) + qrow + c) * NUM_HEADS + h] = lacc[0];
    }
}

// ---------------------------------------------------------------------------
// Kernel 3: combine key-split partials + residual add + LayerNorm.
// In place on P1 (= d_out).
// ---------------------------------------------------------------------------
__global__ __launch_bounds__(256) void ln_kernel(
    float* P1,                     // aliased read/write — no restrict
    const float* __restrict__ P2,
    const float* __restrict__ L1, const float* __restrict__ L2,
    const float* __restrict__ x,
    const float* __restrict__ gamma, const float* __restrict__ beta)
{
    const int lane = threadIdx.x & 63;
    const int wid  = threadIdx.x >> 6;
    const size_t row = (size_t)blockIdx.x * 4 + wid;
    const int h = lane >> 3;                  // head of dims lane*4..lane*4+3

    const float4 a  = ((const float4*)(P1 + row * D_MODEL))[lane];
    const float4 p2 = ((const float4*)(P2 + row * D_MODEL))[lane];
    const float4 xv = ((const float4*)(x + row * D_MODEL))[lane];
    const float inv = 1.0f / (L1[row * NUM_HEADS + h] + L2[row * NUM_HEADS + h]);

    float hv[4];
    hv[0] = (a.x + p2.x) * inv + xv.x;
    hv[1] = (a.y + p2.y) * inv + xv.y;
    hv[2] = (a.z + p2.z) * inv + xv.z;
    hv[3] = (a.w + p2.w) * inv + xv.w;

    float s = hv[0] + hv[1] + hv[2] + hv[3];
    #pragma unroll
    for (int off = 32; off > 0; off >>= 1) s += __shfl_xor(s, off, 64);
    const float mu = s * (1.0f / D_MODEL);

    float d0 = hv[0]-mu, d1 = hv[1]-mu, d2 = hv[2]-mu, d3 = hv[3]-mu;
    float ss = d0*d0 + d1*d1 + d2*d2 + d3*d3;
    #pragma unroll
    for (int off = 32; off > 0; off >>= 1) ss += __shfl_xor(ss, off, 64);
    const float rs = rsqrtf(ss * (1.0f / D_MODEL) + LN_EPS);

    const float4 g  = ((const float4*)gamma)[lane];
    const float4 bb = ((const float4*)beta)[lane];
    float4 y;
    y.x = g.x * d0 * rs + bb.x;
    y.y = g.y * d1 * rs + bb.y;
    y.z = g.z * d2 * rs + bb.z;
    y.w = g.w * d3 * rs + bb.w;
    ((float4*)(P1 + row * D_MODEL))[lane] = y;
}

// ---------------------------------------------------------------------------
extern "C" void kernel_launch(void* const* d_in, const int* in_sizes, int n_in,
                              void* d_out, int out_size, void* d_ws, size_t ws_size,
                              hipStream_t stream)
{
    const float* x     = (const float*)d_in[0];
    const float* pad   = (const float*)d_in[1];
    const float* Wq    = (const float*)d_in[2];
    const float* bq    = (const float*)d_in[3];
    const float* Wk    = (const float*)d_in[4];
    const float* bk    = (const float*)d_in[5];
    const float* Wv    = (const float*)d_in[6];
    const float* bv    = (const float*)d_in[7];
    const float* gamma = (const float*)d_in[8];
    const float* beta  = (const float*)d_in[9];

    const size_t elems = (size_t)NROWS * D_MODEL;       // 2M
    unsigned short* Qh = (unsigned short*)d_ws;          // 4 MB
    unsigned short* Kh = Qh + elems;                     // 4 MB
    unsigned short* Vt = Kh + elems;                     // 4 MB
    float* T2 = (float*)(Vt + elems);                    // 32 KB
    unsigned short* Wt = (unsigned short*)(T2 + NROWS);  // 384 KB
    float* biasc = (float*)(Wt + 768 * 256);             // 3 KB
    float* P2 = biasc + 768;                             // 8 MB
    float* L1 = P2 + elems;                              // 256 KB
    float* L2 = L1 + (size_t)NROWS * NUM_HEADS;          // 256 KB
    unsigned short* xc = (unsigned short*)(L2 + (size_t)NROWS * NUM_HEADS); // 4 MB
    float* P1 = (float*)d_out;                           // partial 1 + final out

    prep_kernel<<<1824, 256, 0, stream>>>(Wq, Wk, Wv, bq, bk, bv, pad, x,
                                          Wt, biasc, T2, xc);
    qkv_mfma_kernel<<<(NROWS / 64) * 12, 256, 0, stream>>>(xc, Wt, biasc,
                                                           Qh, Kh, Vt);
    attn_mfma_kernel<<<BATCH * NUM_HEADS * (SEQ / 64) * 2, 256, 0, stream>>>(
        Qh, Kh, Vt, T2, P1, P2, L1, L2);
    ln_kernel<<<NROWS / 4, 256, 0, stream>>>(P1, P2, L1, L2, x, gamma, beta);
}